// Round 2
// baseline (15416.267 us; speedup 1.0000x reference)
//
#include <hip/hip_runtime.h>
#include <hip/hip_bf16.h>

#define N_ENT   100000
#define N_REL   24
#define N_BASES 8
#define HID     256
#define N_EDGES 1000000
#define N_TRIPLES 65536

// ---------------- workspace layout (bytes) ----------------
// cnt      : N_ENT*N_REL int           @ 0          (9,600,000)
// small    : hist/offs/cursor/tileoffs @ 9,600,000  (4,096)
// srcS     : 1M int                    @ 9,604,096
// dstS     : 1M int                    @ 13,604,096
// normS    : 1M float                  @ 17,604,096
// W        : 24*256*256 float          @ 21,604,096 (6,291,456)
// h1       : 100000*256 float          @ 27,895,552 (102,400,000)  pre-ReLU
// h2       : 100000*256 float          @ 130,295,552(102,400,000)  pre-ReLU
// total ~233 MB

__device__ __forceinline__ void atomF(float* p, float v) {
#if defined(__HIP_PLATFORM_AMD__)
    unsafeAtomicAdd(p, v);   // global_atomic_add_f32 on gfx950
#else
    atomicAdd(p, v);
#endif
}

// ---- count (dst,rel) pairs + relation histogram ----
__global__ __launch_bounds__(256) void count_kernel(
    const int* __restrict__ src, const int* __restrict__ dst,
    const int* __restrict__ et, int* __restrict__ cnt, int* __restrict__ hist)
{
    __shared__ int lhist[N_REL];
    if (threadIdx.x < N_REL) lhist[threadIdx.x] = 0;
    __syncthreads();
    int stride = gridDim.x * blockDim.x;
    for (int e = blockIdx.x * blockDim.x + threadIdx.x; e < N_EDGES; e += stride) {
        int d = dst[e], t = et[e];
        atomicAdd(&cnt[d * N_REL + t], 1);
        atomicAdd(&lhist[t], 1);
    }
    __syncthreads();
    if (threadIdx.x < N_REL) atomicAdd(&hist[threadIdx.x], lhist[threadIdx.x]);
}

// ---- exclusive prefix over 24 relations + tile offsets ----
__global__ void prefix_kernel(const int* __restrict__ hist, int* offs,
                              int* cursor, int* tileoffs)
{
    if (threadIdx.x == 0) {
        int off = 0, toff = 0;
        for (int r = 0; r < N_REL; ++r) {
            offs[r] = off; cursor[r] = off; tileoffs[r] = toff;
            off  += hist[r];
            toff += (hist[r] + 63) >> 6;
        }
        offs[N_REL] = off; tileoffs[N_REL] = toff;
    }
}

// ---- bucket edges by relation (block-aggregated cursor atomics) ----
#define SC_CHUNK 512
__global__ __launch_bounds__(256) void scatter_kernel(
    const int* __restrict__ src, const int* __restrict__ dst,
    const int* __restrict__ et, const int* __restrict__ cnt, int* cursor,
    int* __restrict__ srcS, int* __restrict__ dstS, float* __restrict__ normS)
{
    __shared__ int lhist[N_REL];
    __shared__ int lbase[N_REL];
    int tid = threadIdx.x;
    int base_e = blockIdx.x * SC_CHUNK;
    if (tid < N_REL) lhist[tid] = 0;
    __syncthreads();
    int myrank[2], myet[2];
    #pragma unroll
    for (int q = 0; q < 2; ++q) {
        int e = base_e + q * 256 + tid;
        if (e < N_EDGES) { myet[q] = et[e]; myrank[q] = atomicAdd(&lhist[myet[q]], 1); }
    }
    __syncthreads();
    if (tid < N_REL && lhist[tid] > 0) lbase[tid] = atomicAdd(&cursor[tid], lhist[tid]);
    __syncthreads();
    #pragma unroll
    for (int q = 0; q < 2; ++q) {
        int e = base_e + q * 256 + tid;
        if (e < N_EDGES) {
            int pos = lbase[myet[q]] + myrank[q];
            int d = dst[e];
            srcS[pos] = src[e];
            dstS[pos] = d;
            normS[pos] = 1.0f / (float)max(cnt[d * N_REL + myet[q]], 1);
        }
    }
}

// ---- W[r] = sum_b comp[r,b] * basis[b] ----
__global__ __launch_bounds__(256) void makew_kernel(
    const float* __restrict__ basis, const float* __restrict__ comp,
    float* __restrict__ W)
{
    int stride = gridDim.x * blockDim.x;
    for (int idx = blockIdx.x * blockDim.x + threadIdx.x; idx < N_REL * HID * HID;
         idx += stride) {
        int r  = idx >> 16;        // / 65536 (HID*HID)
        int ij = idx & 65535;
        float acc = 0.f;
        #pragma unroll
        for (int b = 0; b < N_BASES; ++b)
            acc += comp[r * N_BASES + b] * basis[b * HID * HID + ij];
        W[idx] = acc;
    }
}

// ---- out = act(x) @ root + bias  (64 rows x 256 cols per block) ----
// RELU_IN: apply ReLU to x during staging (x stored pre-activation).
template <bool RELU_IN>
__global__ __launch_bounds__(256) void root_gemm(
    const float* __restrict__ x, const float* __restrict__ root,
    const float* __restrict__ bias, float* __restrict__ out)
{
    __shared__ float As[64][HID];
    int tid = threadIdx.x;
    int row0 = blockIdx.x * 64;
    for (int it = 0; it < 16; ++it) {
        int row = (it << 2) + (tid >> 6);
        int c4  = (tid & 63) << 2;
        int grow = row0 + row;
        float4 v = make_float4(0.f, 0.f, 0.f, 0.f);
        if (grow < N_ENT) v = *(const float4*)(x + (size_t)grow * HID + c4);
        if (RELU_IN) {
            v.x = fmaxf(v.x, 0.f); v.y = fmaxf(v.y, 0.f);
            v.z = fmaxf(v.z, 0.f); v.w = fmaxf(v.w, 0.f);
        }
        *(float4*)&As[row][c4] = v;
    }
    __syncthreads();
    int eg = tid >> 5, cg = tid & 31;
    const float* wp = root + (cg << 3);
    float acc[8][8] = {{0.f}};
    for (int k = 0; k < HID; k += 4) {
        float4 a4[8];
        #pragma unroll
        for (int i = 0; i < 8; ++i) a4[i] = *(const float4*)&As[(eg << 3) + i][k];
        #pragma unroll
        for (int kk = 0; kk < 4; ++kk) {
            float4 w0 = *(const float4*)(wp + (size_t)(k + kk) * HID);
            float4 w1 = *(const float4*)(wp + (size_t)(k + kk) * HID + 4);
            #pragma unroll
            for (int i = 0; i < 8; ++i) {
                float a = kk == 0 ? a4[i].x : kk == 1 ? a4[i].y : kk == 2 ? a4[i].z : a4[i].w;
                acc[i][0] += a * w0.x; acc[i][1] += a * w0.y;
                acc[i][2] += a * w0.z; acc[i][3] += a * w0.w;
                acc[i][4] += a * w1.x; acc[i][5] += a * w1.y;
                acc[i][6] += a * w1.z; acc[i][7] += a * w1.w;
            }
        }
    }
    float4 b0 = *(const float4*)(bias + (cg << 3));
    float4 b1 = *(const float4*)(bias + (cg << 3) + 4);
    #pragma unroll
    for (int i = 0; i < 8; ++i) {
        int grow = row0 + (eg << 3) + i;
        if (grow < N_ENT) {
            float4 o0 = make_float4(acc[i][0] + b0.x, acc[i][1] + b0.y,
                                    acc[i][2] + b0.z, acc[i][3] + b0.w);
            float4 o1 = make_float4(acc[i][4] + b1.x, acc[i][5] + b1.y,
                                    acc[i][6] + b1.z, acc[i][7] + b1.w);
            *(float4*)(out + (size_t)grow * HID + (cg << 3))     = o0;
            *(float4*)(out + (size_t)grow * HID + (cg << 3) + 4) = o1;
        }
    }
}

// ---- per-relation gathered GEMM with atomic scatter epilogue ----
// block = 64 edges x 256 cols; C = (norm * act(x[src])) @ W_r ; out[dst] += C
template <bool RELU_IN>
__global__ __launch_bounds__(256) void edge_gemm(
    const float* __restrict__ x, const float* __restrict__ W,
    const int* __restrict__ srcS, const int* __restrict__ dstS,
    const float* __restrict__ normS, const int* __restrict__ offs,
    const int* __restrict__ tileoffs, float* __restrict__ out)
{
    __shared__ float As[64][HID];
    int b = blockIdx.x;
    if (b >= tileoffs[N_REL]) return;
    int r = 0;
    while (tileoffs[r + 1] <= b) ++r;       // <=24 scalar iters
    int e0 = offs[r] + ((b - tileoffs[r]) << 6);
    int e1 = min(offs[r + 1], e0 + 64);
    int ne = e1 - e0;
    const float* Wr = W + (size_t)r * HID * HID;

    int tid = threadIdx.x;
    for (int it = 0; it < 16; ++it) {
        int row = (it << 2) + (tid >> 6);
        int c4  = (tid & 63) << 2;
        float4 v = make_float4(0.f, 0.f, 0.f, 0.f);
        float nrm = 0.f;
        if (row < ne) {
            int s = srcS[e0 + row];
            nrm = normS[e0 + row];
            v = *(const float4*)(x + (size_t)s * HID + c4);
        }
        if (RELU_IN) {
            v.x = fmaxf(v.x, 0.f); v.y = fmaxf(v.y, 0.f);
            v.z = fmaxf(v.z, 0.f); v.w = fmaxf(v.w, 0.f);
        }
        v.x *= nrm; v.y *= nrm; v.z *= nrm; v.w *= nrm;
        *(float4*)&As[row][c4] = v;
    }
    __syncthreads();

    int eg = tid >> 5, cg = tid & 31;
    const float* wp = Wr + (cg << 3);
    float acc[8][8] = {{0.f}};
    for (int k = 0; k < HID; k += 4) {
        float4 a4[8];
        #pragma unroll
        for (int i = 0; i < 8; ++i) a4[i] = *(const float4*)&As[(eg << 3) + i][k];
        #pragma unroll
        for (int kk = 0; kk < 4; ++kk) {
            float4 w0 = *(const float4*)(wp + (size_t)(k + kk) * HID);
            float4 w1 = *(const float4*)(wp + (size_t)(k + kk) * HID + 4);
            #pragma unroll
            for (int i = 0; i < 8; ++i) {
                float a = kk == 0 ? a4[i].x : kk == 1 ? a4[i].y : kk == 2 ? a4[i].z : a4[i].w;
                acc[i][0] += a * w0.x; acc[i][1] += a * w0.y;
                acc[i][2] += a * w0.z; acc[i][3] += a * w0.w;
                acc[i][4] += a * w1.x; acc[i][5] += a * w1.y;
                acc[i][6] += a * w1.z; acc[i][7] += a * w1.w;
            }
        }
    }
    #pragma unroll
    for (int i = 0; i < 8; ++i) {
        int e = (eg << 3) + i;
        if (e < ne) {
            int drow = dstS[e0 + e];
            float* op = out + (size_t)drow * HID + (cg << 3);
            #pragma unroll
            for (int j = 0; j < 8; ++j) atomF(op + j, acc[i][j]);
        }
    }
}

// ---- DistMult: one wave per triple; h2 is pre-ReLU so apply here ----
__global__ __launch_bounds__(256) void distmult_kernel(
    const float* __restrict__ h2, const float* __restrict__ rel,
    const int* __restrict__ heads, const int* __restrict__ rels,
    const int* __restrict__ tails, float* __restrict__ scores)
{
    int tid = threadIdx.x;
    int tr = blockIdx.x * 4 + (tid >> 6);
    int lane = tid & 63;
    if (tr >= N_TRIPLES) return;
    int h = heads[tr], r = rels[tr], t = tails[tr];
    float4 a = *(const float4*)(h2 + (size_t)h * HID + lane * 4);
    float4 bb = *(const float4*)(rel + (size_t)r * HID + lane * 4);
    float4 c = *(const float4*)(h2 + (size_t)t * HID + lane * 4);
    a.x = fmaxf(a.x, 0.f); a.y = fmaxf(a.y, 0.f); a.z = fmaxf(a.z, 0.f); a.w = fmaxf(a.w, 0.f);
    c.x = fmaxf(c.x, 0.f); c.y = fmaxf(c.y, 0.f); c.z = fmaxf(c.z, 0.f); c.w = fmaxf(c.w, 0.f);
    float acc = a.x * bb.x * c.x + a.y * bb.y * c.y + a.z * bb.z * c.z + a.w * bb.w * c.w;
    #pragma unroll
    for (int off = 32; off >= 1; off >>= 1) acc += __shfl_xor(acc, off, 64);
    if (lane == 0) scores[tr] = acc;
}

extern "C" void kernel_launch(void* const* d_in, const int* in_sizes, int n_in,
                              void* d_out, int out_size, void* d_ws, size_t ws_size,
                              hipStream_t stream)
{
    const float* entity  = (const float*)d_in[0];
    const float* rel_emb = (const float*)d_in[1];
    const float* basis1  = (const float*)d_in[2];
    const float* comp1   = (const float*)d_in[3];
    const float* root1   = (const float*)d_in[4];
    const float* bias1   = (const float*)d_in[5];
    const float* basis2  = (const float*)d_in[6];
    const float* comp2   = (const float*)d_in[7];
    const float* root2   = (const float*)d_in[8];
    const float* bias2   = (const float*)d_in[9];
    const int* eidx  = (const int*)d_in[10];
    const int* etype = (const int*)d_in[11];
    const int* heads = (const int*)d_in[12];
    const int* rels  = (const int*)d_in[13];
    const int* tails = (const int*)d_in[14];
    const int* src = eidx;
    const int* dst = eidx + N_EDGES;

    char* ws = (char*)d_ws;
    int*   cnt      = (int*)(ws + 0);
    int*   small    = (int*)(ws + 9600000);
    int*   hist     = small;
    int*   offs     = small + 32;
    int*   cursor   = small + 64;
    int*   tileoffs = small + 96;
    int*   srcS  = (int*)(ws + 9604096);
    int*   dstS  = (int*)(ws + 13604096);
    float* normS = (float*)(ws + 17604096);
    float* Wbuf  = (float*)(ws + 21604096);
    float* h1    = (float*)(ws + 27895552);   // pre-ReLU layer-1 output
    float* h2    = (float*)(ws + 130295552);  // pre-ReLU layer-2 output

    hipMemsetAsync(cnt, 0, (size_t)N_ENT * N_REL * sizeof(int), stream);
    hipMemsetAsync(small, 0, 4096, stream);

    count_kernel<<<2048, 256, 0, stream>>>(src, dst, etype, cnt, hist);
    prefix_kernel<<<1, 64, 0, stream>>>(hist, offs, cursor, tileoffs);
    scatter_kernel<<<(N_EDGES + SC_CHUNK - 1) / SC_CHUNK, 256, 0, stream>>>(
        src, dst, etype, cnt, cursor, srcS, dstS, normS);

    int egrid = N_EDGES / 64 + N_REL;   // upper bound on tiles
    int rgrid = (N_ENT + 63) / 64;

    // ---- layer 1 (inputs are raw entity embeddings: no input ReLU) ----
    makew_kernel<<<2048, 256, 0, stream>>>(basis1, comp1, Wbuf);
    root_gemm<false><<<rgrid, 256, 0, stream>>>(entity, root1, bias1, h1);
    edge_gemm<false><<<egrid, 256, 0, stream>>>(entity, Wbuf, srcS, dstS, normS,
                                                offs, tileoffs, h1);

    // ---- layer 2 (h1 is pre-ReLU: apply ReLU on load) ----
    makew_kernel<<<2048, 256, 0, stream>>>(basis2, comp2, Wbuf);
    root_gemm<true><<<rgrid, 256, 0, stream>>>(h1, root2, bias2, h2);
    edge_gemm<true><<<egrid, 256, 0, stream>>>(h1, Wbuf, srcS, dstS, normS,
                                               offs, tileoffs, h2);

    // ---- DistMult (h2 pre-ReLU: apply ReLU on gather) ----
    distmult_kernel<<<N_TRIPLES / 4, 256, 0, stream>>>(
        h2, rel_emb, heads, rels, tails, (float*)d_out);
}

// Round 3
// 2877.072 us; speedup vs baseline: 5.3583x; 5.3583x over previous
//
#include <hip/hip_runtime.h>
#include <hip/hip_bf16.h>

#define N_ENT   100000
#define N_REL   24
#define N_BASES 8
#define HID     256
#define N_EDGES 1000000
#define N_TRIPLES 65536

// ---------------- workspace layout (bytes) ----------------
// cnt      : N_ENT*N_REL int           @ 0          (9,600,000)
// small    : hist/offs/cursor/tileoffs @ 9,600,000  (4,096)
// srcS     : 1M int                    @ 9,604,096
// dstS     : 1M int                    @ 13,604,096
// normS    : 1M float                  @ 17,604,096
// Whi      : 24*65536 ushort (packed)  @ 21,604,096 (3,145,728)
// Wlo      : 24*65536 ushort (packed)  @ 24,749,824 (3,145,728)
// h1       : 100000*256 float          @ 27,895,552 (102,400,000)  pre-ReLU
// h2       : 100000*256 float          @ 130,295,552(102,400,000)  pre-ReLU
// total ~233 MB

typedef __attribute__((ext_vector_type(8))) short bf16x8;
typedef __attribute__((ext_vector_type(4))) float f32x4;

__device__ __forceinline__ void atomF(float* p, float v) {
#if defined(__HIP_PLATFORM_AMD__)
    unsafeAtomicAdd(p, v);   // fire-and-forget global_atomic_add_f32
#else
    atomicAdd(p, v);
#endif
}

__device__ __forceinline__ unsigned short f2bf(float f) {   // RNE, no NaN inputs
    unsigned int u = __builtin_bit_cast(unsigned int, f);
    u += 0x7fffu + ((u >> 16) & 1u);
    return (unsigned short)(u >> 16);
}
__device__ __forceinline__ float bf2f(unsigned short h) {
    return __builtin_bit_cast(float, (unsigned int)h << 16);
}

// ---- count (dst,rel) pairs + relation histogram ----
__global__ __launch_bounds__(256) void count_kernel(
    const int* __restrict__ src, const int* __restrict__ dst,
    const int* __restrict__ et, int* __restrict__ cnt, int* __restrict__ hist)
{
    __shared__ int lhist[N_REL];
    if (threadIdx.x < N_REL) lhist[threadIdx.x] = 0;
    __syncthreads();
    int stride = gridDim.x * blockDim.x;
    for (int e = blockIdx.x * blockDim.x + threadIdx.x; e < N_EDGES; e += stride) {
        int d = dst[e], t = et[e];
        atomicAdd(&cnt[d * N_REL + t], 1);
        atomicAdd(&lhist[t], 1);
    }
    __syncthreads();
    if (threadIdx.x < N_REL) atomicAdd(&hist[threadIdx.x], lhist[threadIdx.x]);
}

// ---- exclusive prefix over 24 relations + tile offsets ----
__global__ void prefix_kernel(const int* __restrict__ hist, int* offs,
                              int* cursor, int* tileoffs)
{
    if (threadIdx.x == 0) {
        int off = 0, toff = 0;
        for (int r = 0; r < N_REL; ++r) {
            offs[r] = off; cursor[r] = off; tileoffs[r] = toff;
            off  += hist[r];
            toff += (hist[r] + 63) >> 6;
        }
        offs[N_REL] = off; tileoffs[N_REL] = toff;
    }
}

// ---- bucket edges by relation (block-aggregated cursor atomics) ----
#define SC_CHUNK 512
__global__ __launch_bounds__(256) void scatter_kernel(
    const int* __restrict__ src, const int* __restrict__ dst,
    const int* __restrict__ et, const int* __restrict__ cnt, int* cursor,
    int* __restrict__ srcS, int* __restrict__ dstS, float* __restrict__ normS)
{
    __shared__ int lhist[N_REL];
    __shared__ int lbase[N_REL];
    int tid = threadIdx.x;
    int base_e = blockIdx.x * SC_CHUNK;
    if (tid < N_REL) lhist[tid] = 0;
    __syncthreads();
    int myrank[2], myet[2];
    #pragma unroll
    for (int q = 0; q < 2; ++q) {
        int e = base_e + q * 256 + tid;
        if (e < N_EDGES) { myet[q] = et[e]; myrank[q] = atomicAdd(&lhist[myet[q]], 1); }
    }
    __syncthreads();
    if (tid < N_REL && lhist[tid] > 0) lbase[tid] = atomicAdd(&cursor[tid], lhist[tid]);
    __syncthreads();
    #pragma unroll
    for (int q = 0; q < 2; ++q) {
        int e = base_e + q * 256 + tid;
        if (e < N_EDGES) {
            int pos = lbase[myet[q]] + myrank[q];
            int d = dst[e];
            srcS[pos] = src[e];
            dstS[pos] = d;
            normS[pos] = 1.0f / (float)max(cnt[d * N_REL + myet[q]], 1);
        }
    }
}

// ---- W packed for MFMA B-fragments, split into bf16 hi/lo ----
// layout (ushort idx): ((r*8 + k/32)*256 + col)*32 + (k&31)
// one thread per (r, kb, q, col): 8 consecutive k (j=0..7)
__global__ __launch_bounds__(256) void makew_pk(
    const float* __restrict__ basis, const float* __restrict__ comp,
    unsigned short* __restrict__ Wh, unsigned short* __restrict__ Wl)
{
    int idx = blockIdx.x * 256 + threadIdx.x;       // 24*8*4*256 = 196608
    if (idx >= N_REL * 8 * 4 * 256) return;
    int col = idx & 255;
    int q   = (idx >> 8) & 3;
    int kb  = (idx >> 10) & 7;
    int r   = idx >> 13;
    float cf[N_BASES];
    #pragma unroll
    for (int b = 0; b < N_BASES; ++b) cf[b] = comp[r * N_BASES + b];
    unsigned short hh[8] __attribute__((aligned(16)));
    unsigned short ll[8] __attribute__((aligned(16)));
    #pragma unroll
    for (int j = 0; j < 8; ++j) {
        int k = kb * 32 + q * 8 + j;
        float acc = 0.f;
        #pragma unroll
        for (int b = 0; b < N_BASES; ++b)
            acc += cf[b] * basis[(b << 16) + (k << 8) + col];
        unsigned short h = f2bf(acc);
        unsigned short l = f2bf(acc - bf2f(h));
        hh[j] = h; ll[j] = l;
    }
    size_t base = ((size_t)(r * 8 + kb) * 256 + col) * 32 + q * 8;
    *(uint4*)&Wh[base] = *(const uint4*)hh;
    *(uint4*)&Wl[base] = *(const uint4*)ll;
}

// ---- out = act(x) @ root + bias  (fp32 vector; 64 rows x 256 cols/block) ----
template <bool RELU_IN>
__global__ __launch_bounds__(256) void root_gemm(
    const float* __restrict__ x, const float* __restrict__ root,
    const float* __restrict__ bias, float* __restrict__ out)
{
    __shared__ float As[64][HID];
    int tid = threadIdx.x;
    int row0 = blockIdx.x * 64;
    for (int it = 0; it < 16; ++it) {
        int row = (it << 2) + (tid >> 6);
        int c4  = (tid & 63) << 2;
        int grow = row0 + row;
        float4 v = make_float4(0.f, 0.f, 0.f, 0.f);
        if (grow < N_ENT) v = *(const float4*)(x + (size_t)grow * HID + c4);
        if (RELU_IN) {
            v.x = fmaxf(v.x, 0.f); v.y = fmaxf(v.y, 0.f);
            v.z = fmaxf(v.z, 0.f); v.w = fmaxf(v.w, 0.f);
        }
        *(float4*)&As[row][c4] = v;
    }
    __syncthreads();
    int eg = tid >> 5, cg = tid & 31;
    const float* wp = root + (cg << 3);
    float acc[8][8] = {{0.f}};
    for (int k = 0; k < HID; k += 4) {
        float4 a4[8];
        #pragma unroll
        for (int i = 0; i < 8; ++i) a4[i] = *(const float4*)&As[(eg << 3) + i][k];
        #pragma unroll
        for (int kk = 0; kk < 4; ++kk) {
            float4 w0 = *(const float4*)(wp + (size_t)(k + kk) * HID);
            float4 w1 = *(const float4*)(wp + (size_t)(k + kk) * HID + 4);
            #pragma unroll
            for (int i = 0; i < 8; ++i) {
                float a = kk == 0 ? a4[i].x : kk == 1 ? a4[i].y : kk == 2 ? a4[i].z : a4[i].w;
                acc[i][0] += a * w0.x; acc[i][1] += a * w0.y;
                acc[i][2] += a * w0.z; acc[i][3] += a * w0.w;
                acc[i][4] += a * w1.x; acc[i][5] += a * w1.y;
                acc[i][6] += a * w1.z; acc[i][7] += a * w1.w;
            }
        }
    }
    float4 b0 = *(const float4*)(bias + (cg << 3));
    float4 b1 = *(const float4*)(bias + (cg << 3) + 4);
    #pragma unroll
    for (int i = 0; i < 8; ++i) {
        int grow = row0 + (eg << 3) + i;
        if (grow < N_ENT) {
            float4 o0 = make_float4(acc[i][0] + b0.x, acc[i][1] + b0.y,
                                    acc[i][2] + b0.z, acc[i][3] + b0.w);
            float4 o1 = make_float4(acc[i][4] + b1.x, acc[i][5] + b1.y,
                                    acc[i][6] + b1.z, acc[i][7] + b1.w);
            *(float4*)(out + (size_t)grow * HID + (cg << 3))     = o0;
            *(float4*)(out + (size_t)grow * HID + (cg << 3) + 4) = o1;
        }
    }
}

// ---- MFMA edge GEMM: C = (norm*act(x[src])) @ W_r ; out[dst] += C ----
// tile: 64 edges x 256 cols, 4 waves (wave w -> cols w*64..w*64+63).
// split-bf16 3-term: C = Ah@Wh + Ah@Wl + Al@Wh (fp32 accumulate).
// A staged in LDS hi/lo bf16 with XOR-16B swizzle (T2); B from packed global.
template <bool RELU_IN>
__global__ __launch_bounds__(256, 2) void edge_gemm_mfma(
    const float* __restrict__ x,
    const unsigned short* __restrict__ Wh, const unsigned short* __restrict__ Wl,
    const int* __restrict__ srcS, const int* __restrict__ dstS,
    const float* __restrict__ normS, const int* __restrict__ offs,
    const int* __restrict__ tileoffs, float* __restrict__ out)
{
    __shared__ unsigned short Ah[64 * HID];   // 32 KB
    __shared__ unsigned short Al[64 * HID];   // 32 KB
    int b = blockIdx.x;
    if (b >= tileoffs[N_REL]) return;
    int r = 0;
    while (tileoffs[r + 1] <= b) ++r;
    int e0 = offs[r] + ((b - tileoffs[r]) << 6);
    int e1 = min(offs[r + 1], e0 + 64);
    int ne = e1 - e0;

    int tid = threadIdx.x;
    // ---- stage: fp32 gather -> relu -> *norm -> bf16 hi/lo -> swizzled LDS ----
    for (int it = 0; it < 16; ++it) {
        int row = (it << 2) + (tid >> 6);
        int c4  = (tid & 63) << 2;                 // element col (multiple of 4)
        float4 v = make_float4(0.f, 0.f, 0.f, 0.f);
        float nrm = 0.f;
        if (row < ne) {
            int s = srcS[e0 + row];
            nrm = normS[e0 + row];
            v = *(const float4*)(x + (size_t)s * HID + c4);
        }
        if (RELU_IN) {
            v.x = fmaxf(v.x, 0.f); v.y = fmaxf(v.y, 0.f);
            v.z = fmaxf(v.z, 0.f); v.w = fmaxf(v.w, 0.f);
        }
        v.x *= nrm; v.y *= nrm; v.z *= nrm; v.w *= nrm;
        unsigned short hh[4] __attribute__((aligned(8)));
        unsigned short ll[4] __attribute__((aligned(8)));
        float vv[4] = {v.x, v.y, v.z, v.w};
        #pragma unroll
        for (int j = 0; j < 4; ++j) {
            unsigned short h = f2bf(vv[j]);
            hh[j] = h;
            ll[j] = f2bf(vv[j] - bf2f(h));
        }
        int byt = (c4 << 1) ^ ((row & 7) << 4);    // swizzled byte off in 512B row
        int us  = (row << 8) + (byt >> 1);         // ushort index
        *(ushort4*)&Ah[us] = *(const ushort4*)hh;
        *(ushort4*)&Al[us] = *(const ushort4*)ll;
    }
    __syncthreads();

    int wv = tid >> 6;            // wave 0..3 -> col base wv*64
    int lane = tid & 63;
    int lc = lane & 15, lq = lane >> 4;
    const unsigned short* WhR = Wh + ((size_t)r << 16);
    const unsigned short* WlR = Wl + ((size_t)r << 16);

    f32x4 acc[4][4];
    #pragma unroll
    for (int mi = 0; mi < 4; ++mi)
        #pragma unroll
        for (int ni = 0; ni < 4; ++ni) acc[mi][ni] = (f32x4)0.f;

    for (int kb = 0; kb < 8; ++kb) {
        bf16x8 ah[4], al[4], bh[4], bl[4];
        #pragma unroll
        for (int mi = 0; mi < 4; ++mi) {
            int row = mi * 16 + lc;
            int byt = ((kb << 6) + (lq << 4)) ^ ((row & 7) << 4);
            int us  = (row << 8) + (byt >> 1);
            ah[mi] = *(const bf16x8*)&Ah[us];
            al[mi] = *(const bf16x8*)&Al[us];
        }
        #pragma unroll
        for (int ni = 0; ni < 4; ++ni) {
            int col = (wv << 6) + ni * 16 + lc;
            size_t bidx = ((size_t)(kb << 8) + col) * 32 + (lq << 3);
            bh[ni] = *(const bf16x8*)&WhR[bidx];
            bl[ni] = *(const bf16x8*)&WlR[bidx];
        }
        #pragma unroll
        for (int mi = 0; mi < 4; ++mi)
            #pragma unroll
            for (int ni = 0; ni < 4; ++ni) {
                acc[mi][ni] = __builtin_amdgcn_mfma_f32_16x16x32_bf16(
                    ah[mi], bh[ni], acc[mi][ni], 0, 0, 0);
                acc[mi][ni] = __builtin_amdgcn_mfma_f32_16x16x32_bf16(
                    ah[mi], bl[ni], acc[mi][ni], 0, 0, 0);
                acc[mi][ni] = __builtin_amdgcn_mfma_f32_16x16x32_bf16(
                    al[mi], bh[ni], acc[mi][ni], 0, 0, 0);
            }
    }

    // ---- epilogue: atomic scatter; 16 consecutive dwords per 16-lane group ----
    #pragma unroll
    for (int mi = 0; mi < 4; ++mi) {
        #pragma unroll
        for (int rr = 0; rr < 4; ++rr) {
            int e = mi * 16 + (lq << 2) + rr;      // C row = lq*4+rr
            if (e < ne) {
                int drow = dstS[e0 + e];
                float* op = out + (size_t)drow * HID + (wv << 6) + lc;
                #pragma unroll
                for (int ni = 0; ni < 4; ++ni)
                    atomF(op + ni * 16, acc[mi][ni][rr]);
            }
        }
    }
}

// ---- DistMult: one wave per triple; h2 is pre-ReLU so apply here ----
__global__ __launch_bounds__(256) void distmult_kernel(
    const float* __restrict__ h2, const float* __restrict__ rel,
    const int* __restrict__ heads, const int* __restrict__ rels,
    const int* __restrict__ tails, float* __restrict__ scores)
{
    int tid = threadIdx.x;
    int tr = blockIdx.x * 4 + (tid >> 6);
    int lane = tid & 63;
    if (tr >= N_TRIPLES) return;
    int h = heads[tr], r = rels[tr], t = tails[tr];
    float4 a = *(const float4*)(h2 + (size_t)h * HID + lane * 4);
    float4 bb = *(const float4*)(rel + (size_t)r * HID + lane * 4);
    float4 c = *(const float4*)(h2 + (size_t)t * HID + lane * 4);
    a.x = fmaxf(a.x, 0.f); a.y = fmaxf(a.y, 0.f); a.z = fmaxf(a.z, 0.f); a.w = fmaxf(a.w, 0.f);
    c.x = fmaxf(c.x, 0.f); c.y = fmaxf(c.y, 0.f); c.z = fmaxf(c.z, 0.f); c.w = fmaxf(c.w, 0.f);
    float acc = a.x * bb.x * c.x + a.y * bb.y * c.y + a.z * bb.z * c.z + a.w * bb.w * c.w;
    #pragma unroll
    for (int off = 32; off >= 1; off >>= 1) acc += __shfl_xor(acc, off, 64);
    if (lane == 0) scores[tr] = acc;
}

extern "C" void kernel_launch(void* const* d_in, const int* in_sizes, int n_in,
                              void* d_out, int out_size, void* d_ws, size_t ws_size,
                              hipStream_t stream)
{
    const float* entity  = (const float*)d_in[0];
    const float* rel_emb = (const float*)d_in[1];
    const float* basis1  = (const float*)d_in[2];
    const float* comp1   = (const float*)d_in[3];
    const float* root1   = (const float*)d_in[4];
    const float* bias1   = (const float*)d_in[5];
    const float* basis2  = (const float*)d_in[6];
    const float* comp2   = (const float*)d_in[7];
    const float* root2   = (const float*)d_in[8];
    const float* bias2   = (const float*)d_in[9];
    const int* eidx  = (const int*)d_in[10];
    const int* etype = (const int*)d_in[11];
    const int* heads = (const int*)d_in[12];
    const int* rels  = (const int*)d_in[13];
    const int* tails = (const int*)d_in[14];
    const int* src = eidx;
    const int* dst = eidx + N_EDGES;

    char* ws = (char*)d_ws;
    int*   cnt      = (int*)(ws + 0);
    int*   small    = (int*)(ws + 9600000);
    int*   hist     = small;
    int*   offs     = small + 32;
    int*   cursor   = small + 64;
    int*   tileoffs = small + 96;
    int*   srcS  = (int*)(ws + 9604096);
    int*   dstS  = (int*)(ws + 13604096);
    float* normS = (float*)(ws + 17604096);
    unsigned short* Whi = (unsigned short*)(ws + 21604096);
    unsigned short* Wlo = (unsigned short*)(ws + 24749824);
    float* h1    = (float*)(ws + 27895552);   // pre-ReLU layer-1 output
    float* h2    = (float*)(ws + 130295552);  // pre-ReLU layer-2 output

    hipMemsetAsync(cnt, 0, (size_t)N_ENT * N_REL * sizeof(int), stream);
    hipMemsetAsync(small, 0, 4096, stream);

    count_kernel<<<2048, 256, 0, stream>>>(src, dst, etype, cnt, hist);
    prefix_kernel<<<1, 64, 0, stream>>>(hist, offs, cursor, tileoffs);
    scatter_kernel<<<(N_EDGES + SC_CHUNK - 1) / SC_CHUNK, 256, 0, stream>>>(
        src, dst, etype, cnt, cursor, srcS, dstS, normS);

    int egrid = N_EDGES / 64 + N_REL;   // upper bound on tiles
    int rgrid = (N_ENT + 63) / 64;
    int wgrid = (N_REL * 8 * 4 * 256 + 255) / 256;

    // ---- layer 1 (raw entity embeddings: no input ReLU) ----
    makew_pk<<<wgrid, 256, 0, stream>>>(basis1, comp1, Whi, Wlo);
    root_gemm<false><<<rgrid, 256, 0, stream>>>(entity, root1, bias1, h1);
    edge_gemm_mfma<false><<<egrid, 256, 0, stream>>>(
        entity, Whi, Wlo, srcS, dstS, normS, offs, tileoffs, h1);

    // ---- layer 2 (h1 pre-ReLU: apply ReLU on load) ----
    makew_pk<<<wgrid, 256, 0, stream>>>(basis2, comp2, Whi, Wlo);
    root_gemm<true><<<rgrid, 256, 0, stream>>>(h1, root2, bias2, h2);
    edge_gemm_mfma<true><<<egrid, 256, 0, stream>>>(
        h1, Whi, Wlo, srcS, dstS, normS, offs, tileoffs, h2);

    // ---- DistMult (h2 pre-ReLU: apply ReLU on gather) ----
    distmult_kernel<<<N_TRIPLES / 4, 256, 0, stream>>>(
        h2, rel_emb, heads, rels, tails, (float*)d_out);
}